// Round 5
// baseline (153.086 us; speedup 1.0000x reference)
//
#include <hip/hip_runtime.h>
#include <math.h>

// CTC-CRF NLL: mean_b( logZ_den(b) - logZ_num(b) ), B=16,T=2048,S=8,L=256.
//
// R16 = R15 (proven: num 2-wave symbol-split pipeline, absmax 0) + den
// time-segment split via 8x8 transfer matrices.
// Evidence den is critical: R13->R15 halved num per-wave work, dispatch
// only 94.5->88us => den (~1023 steps/dir, unchanged) sits at ~88us.
// The den scan is linear: alpha(t) = alpha(t-1)*A_t, A_t[i][j]=T[i][j]em_t[j].
// A segment's composite 8x8 matrix = 8 basis scans. The old den wave wasted
// 8x lane redundancy (64 lanes = 8 replicas of an 8-state scan). One wave
// scans 4 basis columns (one per 16-lane row, duplicated twice -> row_ror
// rotations == rotate-within-8, same trick the real scan uses); 2 waves =
// full matrix. Roles (grid 5B):
//   0 num-fwd (R15)   1 num-bwd (R15)
//   2 den-real: fwd t=1..tq(=tm/2), bwd t=len-1..tq2+1  (~512 steps each)
//   3 den-matF: M_F over t=tq+1..tm      (2 waves x 4 cols, ~512 steps)
//   4 den-matB: M_B over t=tq2..tm+1     (2 waves x 4 cols, ~512 steps)
// Winner composes Z_den = (alpha*M_F)&(M_B*beta) with exact power-of-2
// per-column scales. Only association order changes (ulp-level).

#define LOG2E 1.4426950408889634f
#define LN2   0.69314718055994531f
#define CTL_WSHL1  0x130            // DPP wave_shl:1 (lane63 -> 0)
#define CTL_WSHR1  0x138            // DPP wave_shr:1 (lane0  -> 0)
#define CTL_ROR(r) (0x120 + (r))    // DPP row_ror:r

#define AST(p, v) __hip_atomic_store((p), (v), __ATOMIC_RELAXED, __HIP_MEMORY_SCOPE_AGENT)
#define ALD(p)    __hip_atomic_load((p), __ATOMIC_RELAXED, __HIP_MEMORY_SCOPE_AGENT)

template <int CTRL>
__device__ __forceinline__ float fdpp(float x) {
    return __int_as_float(__builtin_amdgcn_update_dpp(
        0, __float_as_int(x), CTRL, 0xF, 0xF, true));
}
template <int CTRL>
__device__ __forceinline__ int idpp(int x) {
    return __builtin_amdgcn_update_dpp(0, x, CTRL, 0xF, 0xF, true);
}

__device__ __forceinline__ void pin() {      // scheduler fence (MIR-level)
#if __has_builtin(__builtin_amdgcn_sched_barrier)
    __builtin_amdgcn_sched_barrier(0);
#else
    asm volatile("" ::: "memory");
#endif
}

__device__ __forceinline__ float fexp2(float x) {
#if __has_builtin(__builtin_amdgcn_exp2f)
    return __builtin_amdgcn_exp2f(x);
#else
    return exp2f(x);
#endif
}
__device__ __forceinline__ float flog2(float x) {
#if __has_builtin(__builtin_amdgcn_logf)
    return __builtin_amdgcn_logf(x);
#else
    return __log2f(x);
#endif
}
__device__ __forceinline__ float lse2(float a, float b) {   // log2(2^a+2^b)
    float m = fmaxf(a, b);
    float d = fminf(a, b) - m;
    return m + flog2(1.0f + fexp2(d));
}

// ================= numerator forward: one step + inline boundary ==========
#define NFW_STEP {                                                          \
    float2 q0 = st0[tb + k + 1], q1 = st1[tb + k + 1];                      \
    float2 rv = make_float2(0.0f, 0.0f);                                    \
    if (CONS) rv = rEX[k * 64 + 63];                                        \
    float nbE = fdpp<CTL_WSHR1>(E[1]);                                      \
    float nbX = fdpp<CTL_WSHR1>(X[1]);                                      \
    if (CONS && l0) { nbE = rv.x; nbX = rv.y; }                             \
    float nE0 = p0.x * fmaf(nbE,  teeF, nbX  * txeF);                       \
    float nE1 = p1.x * fmaf(E[0], tee1, X[0] * txe1);                       \
    float nX0 = p0.y * fmaf(E[0], tex0, X[0] * txx0);                       \
    float nX1 = p1.y * fmaf(E[1], tex1, X[1] * txx1);                       \
    E[0] = nE0; E[1] = nE1; X[0] = nX0; X[1] = nX1;                         \
    if (!CONS) rEX[(k + 1) * 64 + lane] = make_float2(E[1], X[1]);          \
    if ((k & 7) == 7) {                                                     \
        int rs = 0;                                                         \
        if (CONS) rs = rS[(k >> 3) * 64 + 63];                              \
        float m = fmaxf(fmaxf(E[0], E[1]), fmaxf(X[0], X[1]));              \
        const bool live = (m > 0.0f);                                       \
        const int ex = live ? ((int)(__float_as_uint(m) >> 23) - 126) : 0;  \
        s += ex;                                                            \
        int bs = idpp<CTL_WSHR1>(s);                                        \
        if (CONS && l0) bs = rs;                                            \
        if (!live) s = bs;                                                  \
        int d = (g == 0) ? 0 : (bs - s);                                    \
        const int extra = (d > 30) ? d : 0;                                 \
        s += extra; d -= extra;                                             \
        const float fsc = ldexpf(1.0f, -(ex + extra));                      \
        E[0] *= fsc; E[1] *= fsc; X[0] *= fsc; X[1] *= fsc;                 \
        const float fs0 = (g == 0) ? 0.0f : ldexpf(1.0f, d);                \
        teeF = tee0 * fs0; txeF = txe0 * fs0;                               \
        if (!CONS) { rS[(k >> 3) * 64 + lane] = s;                          \
                     rEX[(k + 1) * 64 + lane] = make_float2(E[1], X[1]); }  \
    }                                                                       \
    p0 = q0; p1 = q1; }

template <bool CONS>
__device__ __forceinline__ void nfwd_chunk(
    const float2* st0, const float2* st1,
    float (&E)[2], float (&X)[2], int& s, float& teeF, float& txeF,
    float tee0, float txe0, float tee1, float txe1,
    float tex0, float txx0, float tex1, float txx1,
    int tb, int n, int g, int lane, float2* rEX, int* rS)
{
    const bool l0 = (lane == 0);
    if (!CONS) rEX[lane] = make_float2(E[1], X[1]);   // carry-in slot 0
    float2 p0 = st0[tb], p1 = st1[tb];
    if (n == 16) {
#pragma unroll
        for (int k = 0; k < 16; ++k) NFW_STEP
    } else {
        for (int k = 0; k < n; ++k) NFW_STEP
    }
}

// ================= numerator backward: one step + inline boundary =========
#define NBW_STEP {                                                          \
    float2 q0 = st0[tb - k - 1], q1 = st1[tb - k - 1];                      \
    float rm = 0.0f;                                                        \
    if (CONS) rm = rM[k * 64];                                              \
    float mm0 = p0.x * bE[0];                                               \
    float mm1 = p1.x * bE[1];                                               \
    float m10 = p0.y * bX[0];                                               \
    float m11 = p1.y * bX[1];                                               \
    float mup = fdpp<CTL_WSHL1>(mm0);                                       \
    if (CONS && l63) mup = rm;                                              \
    if (!CONS) rM[k * 64 + lane] = mm0;                                     \
    float nE0 = fmaf(tex0, m10, teeN0 * mm1);                               \
    float nX0 = fmaf(txx0, m10, txeN0 * mm1);                               \
    float nE1 = fmaf(tex1, m11, teeN1F * mup);                              \
    float nX1 = fmaf(txx1, m11, txeN1F * mup);                              \
    bE[0] = nE0; bE[1] = nE1; bX[0] = nX0; bX[1] = nX1;                     \
    if ((k & 7) == 7) {                                                     \
        int rs = 0;                                                         \
        if (CONS) rs = rS[(k >> 3) * 64];                                   \
        float m = fmaxf(fmaxf(bE[0], bE[1]), fmaxf(bX[0], bX[1]));          \
        const bool live = (m > 0.0f);                                       \
        const int ex = live ? ((int)(__float_as_uint(m) >> 23) - 126) : 0;  \
        s += ex;                                                            \
        int bs = idpp<CTL_WSHL1>(s);                                        \
        if (CONS && l63) bs = rs;                                           \
        if (!live) s = bs;                                                  \
        int d = (g == 127) ? 0 : (bs - s);                                  \
        const int extra = (d > 30) ? d : 0;                                 \
        s += extra; d -= extra;                                             \
        const float fsc = ldexpf(1.0f, -(ex + extra));                      \
        bE[0] *= fsc; bE[1] *= fsc; bX[0] *= fsc; bX[1] *= fsc;             \
        const float fs = (g == 127) ? 0.0f : ldexpf(1.0f, d);               \
        teeN1F = teeN1 * fs; txeN1F = txeN1 * fs;                           \
        if (!CONS) rS[(k >> 3) * 64 + lane] = s;                            \
    }                                                                       \
    p0 = q0; p1 = q1; }

template <bool CONS>
__device__ __forceinline__ void nbwd_chunk(
    const float2* st0, const float2* st1,
    float (&bE)[2], float (&bX)[2], int& s, float& teeN1F, float& txeN1F,
    float teeN0, float txeN0, float teeN1, float txeN1,
    float tex0, float txx0, float tex1, float txx1,
    int tb, int n, int g, int lane, float* rM, int* rS)
{
    const bool l63 = (lane == 63);
    float2 p0 = st0[tb], p1 = st1[tb];
    if (n == 16) {
#pragma unroll
        for (int k = 0; k < 16; ++k) NBW_STEP
    } else {
        for (int k = 0; k < n; ++k) NBW_STEP
    }
}

// ---------------- denominator steps (proven) ----------------
__device__ __forceinline__ float denf_step(float al, float emt, const float* Tr) {
    float v1 = fdpp<CTL_ROR(1)>(al);
    float v2 = fdpp<CTL_ROR(2)>(al);
    float v3 = fdpp<CTL_ROR(3)>(al);
    float v4 = fdpp<CTL_ROR(4)>(al);
    float v5 = fdpp<CTL_ROR(5)>(al);
    float v6 = fdpp<CTL_ROR(6)>(al);
    float v7 = fdpp<CTL_ROR(7)>(al);
    float q0 = fmaf(v1, Tr[1], al * Tr[0]);
    float q1 = fmaf(v3, Tr[3], v2 * Tr[2]);
    float q2 = fmaf(v5, Tr[5], v4 * Tr[4]);
    float q3 = fmaf(v7, Tr[7], v6 * Tr[6]);
    return ((q0 + q1) + (q2 + q3)) * emt;
}
__device__ __forceinline__ float denb_step(float al, float emt, const float* TrB) {
    float g  = al * emt;
    float v1 = fdpp<CTL_ROR(7)>(g);
    float v2 = fdpp<CTL_ROR(6)>(g);
    float v3 = fdpp<CTL_ROR(5)>(g);
    float v4 = fdpp<CTL_ROR(4)>(g);
    float v5 = fdpp<CTL_ROR(3)>(g);
    float v6 = fdpp<CTL_ROR(2)>(g);
    float v7 = fdpp<CTL_ROR(1)>(g);
    float q0 = fmaf(v1, TrB[1], g * TrB[0]);
    float q1 = fmaf(v3, TrB[3], v2 * TrB[2]);
    float q2 = fmaf(v5, TrB[5], v4 * TrB[4]);
    float q3 = fmaf(v7, TrB[7], v6 * TrB[6]);
    return (q0 + q1) + (q2 + q3);
}
__device__ __forceinline__ int den_renorm(float& al) {
    float mm = fmaxf(al, fdpp<CTL_ROR(4)>(al));
    mm = fmaxf(mm, fdpp<CTL_ROR(2)>(mm));
    mm = fmaxf(mm, fdpp<CTL_ROR(1)>(mm));
    const int ex = (int)(__float_as_uint(mm) >> 23) - 126;
    al = ldexpf(al, -ex);
    return ex;
}

extern "C" __global__ void __launch_bounds__(128)
crf_fused(const float* __restrict__ em, const float* __restrict__ trans,
          const float* __restrict__ bos, const float* __restrict__ eos,
          const int* __restrict__ lengths, const int* __restrict__ targets,
          const int* __restrict__ tlens,
          float* __restrict__ ws, float* __restrict__ out,
          int B, int T, int S, int L)
{
    extern __shared__ float sm[];
    const int bid  = blockIdx.x;
    const int tid  = threadIdx.x;
    const int lane = tid & 63;
    const int wv   = tid >> 6;
    const int half = S >> 1;                 // = 4
    const int role = bid / B;                // 0 nf, 1 nb, 2 den-real, 3 matF, 4 matB
    const int b    = bid % B;
    const float* gem = em + (size_t)b * T * S;
    const int len = lengths[b];
    const int tm  = (len - 1) >> 1;
    const int P2  = T + 2;                   // padded float2 pitch per stream
    const int RINGF = 8 * P2;                // ring offset (floats)

    float* NF  = ws + 16 + (size_t)b * 640;
    float* NB  = ws + 16 + (size_t)B * 640 + (size_t)b * 640;
    const size_t DENR = 16 + (size_t)(2 * B) * 640;
    const size_t MATF = DENR + (size_t)B * 32;
    const size_t MATB = MATF + (size_t)B * 128;
    int* ticket = (int*)ws;

    // segment boundaries for den split
    const int tq  = tm >> 1;                         // real fwd: 1..tq
    const int dlo = tm + 1, dhi = len - 1;
    const int tq2 = (dhi >= dlo) ? (dlo + ((dhi - dlo) >> 1)) : (dlo - 1);
    // real bwd: dhi..tq2+1 ; matF: tq+1..tm ; matB: tq2..dlo

    // ---------------- staging ----------------
    if (role < 2) {
        // padded transposed streams: s2[j*P2 + t] = (2^em[t][j], 2^em[t][j+4])
        float2* s2 = (float2*)sm;
        for (int t = tid; t < T; t += 128) {
            const float4* gr = (const float4*)(gem + t * S);
            float4 a = gr[0], c4 = gr[1];
            s2[0 * P2 + t] = make_float2(fexp2(a.x * LOG2E), fexp2(c4.x * LOG2E));
            s2[1 * P2 + t] = make_float2(fexp2(a.y * LOG2E), fexp2(c4.y * LOG2E));
            s2[2 * P2 + t] = make_float2(fexp2(a.z * LOG2E), fexp2(c4.z * LOG2E));
            s2[3 * P2 + t] = make_float2(fexp2(a.w * LOG2E), fexp2(c4.w * LOG2E));
        }
    } else {
        // row-interleaved for den: sm[t*8 + 2j+h]
        for (int t = tid; t < T; t += 128) {
            const float4* gr = (const float4*)(gem + t * S);
            float4 a = gr[0], c4 = gr[1];
            float4 w0, w1;
            w0.x = fexp2(a.x * LOG2E); w0.y = fexp2(c4.x * LOG2E);
            w0.z = fexp2(a.y * LOG2E); w0.w = fexp2(c4.y * LOG2E);
            w1.x = fexp2(a.z * LOG2E); w1.y = fexp2(c4.z * LOG2E);
            w1.z = fexp2(a.w * LOG2E); w1.w = fexp2(c4.w * LOG2E);
            ((float4*)sm)[t * 2]     = w0;
            ((float4*)sm)[t * 2 + 1] = w1;
        }
    }
    __syncthreads();

    if (role == 0) {
        // ===== NUMERATOR FORWARD, 2-wave symbol-split pipeline (R15) =====
        const float2* s2v = (const float2*)sm;
        const int g   = (wv << 6) + lane;    // global lane 0..127
        const int u0g = g * 2;
        const int base = b * L;
        const int e0 = targets[base + ((u0g     < L) ? u0g     : (L - 1))];
        const int e1 = targets[base + ((u0g + 1 < L) ? u0g + 1 : (L - 1))];
        const int ep = (u0g > 0) ? targets[base + u0g - 1] : e0;
        const float tee0 = fexp2(trans[ep * S + e0] * LOG2E);
        const float txe0 = fexp2(trans[(ep + half) * S + e0] * LOG2E);
        const float tee1 = fexp2(trans[e0 * S + e1] * LOG2E);
        const float txe1 = fexp2(trans[(e0 + half) * S + e1] * LOG2E);
        const float tex0 = fexp2(trans[e0 * S + e0 + half] * LOG2E);
        const float txx0 = fexp2(trans[(e0 + half) * S + e0 + half] * LOG2E);
        const float tex1 = fexp2(trans[e1 * S + e1 + half] * LOG2E);
        const float txx1 = fexp2(trans[(e1 + half) * S + e1 + half] * LOG2E);
        const float2* st0 = s2v + e0 * P2;
        const float2* st1 = s2v + e1 * P2;
        float E[2] = {0.f, 0.f}, X[2] = {0.f, 0.f};
        int s = 0;
        if (g == 0) E[0] = fexp2(bos[e0] * LOG2E) * st0[0].x;
        float teeF = (g == 0) ? 0.0f : tee0;
        float txeF = (g == 0) ? 0.0f : txe0;

        float2* ringEX = (float2*)(sm + RINGF);       // [2][17][64]
        int*    ringS  = (int*)(sm + RINGF + 4352);   // [2][2][64]
        const int NCH = (tm + 15) >> 4;
        for (int ph = 0; ph <= NCH; ++ph) {
            const int ci = (wv == 0) ? ph : ph - 1;   // producer = wave0
            if (ci >= 0 && ci < NCH) {
                const int tb = 1 + (ci << 4);
                int n = tm - tb + 1; if (n > 16) n = 16;
                float2* rEX = ringEX + (ci & 1) * (17 * 64);
                int*    rS  = ringS  + (ci & 1) * 128;
                if (wv == 0)
                    nfwd_chunk<false>(st0, st1, E, X, s, teeF, txeF,
                                      tee0, txe0, tee1, txe1,
                                      tex0, txx0, tex1, txx1,
                                      tb, n, g, lane, rEX, rS);
                else
                    nfwd_chunk<true>(st0, st1, E, X, s, teeF, txeF,
                                     tee0, txe0, tee1, txe1,
                                     tex0, txx0, tex1, txx1,
                                     tb, n, g, lane, rEX, rS);
            }
            __syncthreads();
        }
        AST(&NF[g * 4 + 0], E[0]);
        AST(&NF[g * 4 + 1], E[1]);
        AST(&NF[g * 4 + 2], X[0]);
        AST(&NF[g * 4 + 3], X[1]);
        AST(&NF[512 + g], __int_as_float(s));
    } else if (role == 1) {
        // ===== NUMERATOR BACKWARD, 2-wave pipeline (R15) =====
        const float2* s2v = (const float2*)sm;
        const int g   = (wv << 6) + lane;
        const int u0g = g * 2;
        const int base = b * L;
        const int e0 = targets[base + ((u0g     < L) ? u0g     : (L - 1))];
        const int e1 = targets[base + ((u0g + 1 < L) ? u0g + 1 : (L - 1))];
        const int e2 = targets[base + ((u0g + 2 < L) ? u0g + 2 : (L - 1))];
        const float tex0 = fexp2(trans[e0 * S + e0 + half] * LOG2E);
        const float txx0 = fexp2(trans[(e0 + half) * S + e0 + half] * LOG2E);
        const float tex1 = fexp2(trans[e1 * S + e1 + half] * LOG2E);
        const float txx1 = fexp2(trans[(e1 + half) * S + e1 + half] * LOG2E);
        const float teeN0 = fexp2(trans[e0 * S + e1] * LOG2E);
        const float txeN0 = fexp2(trans[(e0 + half) * S + e1] * LOG2E);
        float teeN1 = fexp2(trans[e1 * S + e2] * LOG2E);
        float txeN1 = fexp2(trans[(e1 + half) * S + e2] * LOG2E);
        if (g == 127) { teeN1 = 0.0f; txeN1 = 0.0f; }
        const float2* st0 = s2v + e0 * P2;
        const float2* st1 = s2v + e1 * P2;
        float bE[2] = {0.f, 0.f}, bX[2] = {0.f, 0.f};
        const int uf = tlens[b] - 1;
        if (g == (uf >> 1)) {
            const int kf = uf & 1;
            const int ef = kf ? e1 : e0;
            bE[kf] = fexp2(eos[ef] * LOG2E);
            bX[kf] = fexp2(eos[ef + half] * LOG2E);
        }
        int s = 0;
        float teeN1F = teeN1, txeN1F = txeN1;

        float* ringM = sm + RINGF;                    // [2][16][64] floats
        int*   ringS = (int*)(sm + RINGF + 4352);     // [2][2][64]
        const int th = len - 1, tlo = tm + 1;
        const int nbs = th - tlo + 1;
        const int NCH = (nbs > 0) ? ((nbs + 15) >> 4) : 0;
        for (int ph = 0; ph <= NCH; ++ph) {
            const int ci = (wv == 1) ? ph : ph - 1;   // producer = wave1
            if (ci >= 0 && ci < NCH) {
                const int tb = th - (ci << 4);
                int n = tb - tlo + 1; if (n > 16) n = 16;
                float* rM = ringM + (ci & 1) * 1024;
                int*   rS = ringS + (ci & 1) * 128;
                if (wv == 1)
                    nbwd_chunk<false>(st0, st1, bE, bX, s, teeN1F, txeN1F,
                                      teeN0, txeN0, teeN1, txeN1,
                                      tex0, txx0, tex1, txx1,
                                      tb, n, g, lane, rM, rS);
                else
                    nbwd_chunk<true>(st0, st1, bE, bX, s, teeN1F, txeN1F,
                                     teeN0, txeN0, teeN1, txeN1,
                                     tex0, txx0, tex1, txx1,
                                     tb, n, g, lane, rM, rS);
            }
            __syncthreads();
        }
        AST(&NB[g * 4 + 0], bE[0]);
        AST(&NB[g * 4 + 1], bE[1]);
        AST(&NB[g * 4 + 2], bX[0]);
        AST(&NB[g * 4 + 3], bX[1]);
        AST(&NB[512 + g], __int_as_float(s));
    } else if (role == 2) {
        // =================== DEN REAL: fwd 1..tq, bwd dhi..tq2+1 ============
        float* DR = ws + DENR + (size_t)b * 32;
        const int j  = lane & 7;
        const int jj = ((j & 3) << 1) + (j >> 2);
        if (wv == 0) {
            float Tr[8];
#pragma unroll
            for (int r = 0; r < 8; ++r)
                Tr[r] = fexp2(trans[((j - r) & 7) * S + j] * LOG2E);
            float al = fexp2(bos[j] * LOG2E) * sm[jj];
            int sc = 0;
            int t = 1;
            if (t + 3 <= tq) {
                float c0 = sm[t * 8 + jj];
                float c1 = sm[(t + 1) * 8 + jj];
                float c2 = sm[(t + 2) * 8 + jj];
                float c3 = sm[(t + 3) * 8 + jj];
                pin();
                while (t + 7 <= tq) {
                    float d0 = sm[(t + 4) * 8 + jj];
                    float d1 = sm[(t + 5) * 8 + jj];
                    float d2 = sm[(t + 6) * 8 + jj];
                    float d3 = sm[(t + 7) * 8 + jj];
                    pin();
                    al = denf_step(al, c0, Tr);
                    al = denf_step(al, c1, Tr);
                    al = denf_step(al, c2, Tr);
                    al = denf_step(al, c3, Tr);
                    sc += den_renorm(al);
                    c0 = d0; c1 = d1; c2 = d2; c3 = d3;
                    t += 4;
                }
                al = denf_step(al, c0, Tr);
                al = denf_step(al, c1, Tr);
                al = denf_step(al, c2, Tr);
                al = denf_step(al, c3, Tr);
                sc += den_renorm(al);
                t += 4;
            }
            while (t <= tq) { al = denf_step(al, sm[t * 8 + jj], Tr); ++t; }
            if (lane < 8) {
                AST(&DR[j], al);
                if (j == 0) AST(&DR[8], __int_as_float(sc));
            }
        } else {
            float TrB[8];
#pragma unroll
            for (int r = 0; r < 8; ++r)
                TrB[r] = fexp2(trans[j * S + ((j + r) & 7)] * LOG2E);
            float al = fexp2(eos[j] * LOG2E);
            int sc = 0;
            int t = dhi;
            const int tloR = tq2 + 1;
            if (t - 3 >= tloR) {
                float c0 = sm[t * 8 + jj];
                float c1 = sm[(t - 1) * 8 + jj];
                float c2 = sm[(t - 2) * 8 + jj];
                float c3 = sm[(t - 3) * 8 + jj];
                pin();
                while (t - 7 >= tloR) {
                    float d0 = sm[(t - 4) * 8 + jj];
                    float d1 = sm[(t - 5) * 8 + jj];
                    float d2 = sm[(t - 6) * 8 + jj];
                    float d3 = sm[(t - 7) * 8 + jj];
                    pin();
                    al = denb_step(al, c0, TrB);
                    al = denb_step(al, c1, TrB);
                    al = denb_step(al, c2, TrB);
                    al = denb_step(al, c3, TrB);
                    sc += den_renorm(al);
                    c0 = d0; c1 = d1; c2 = d2; c3 = d3;
                    t -= 4;
                }
                al = denb_step(al, c0, TrB);
                al = denb_step(al, c1, TrB);
                al = denb_step(al, c2, TrB);
                al = denb_step(al, c3, TrB);
                sc += den_renorm(al);
                t -= 4;
            }
            while (t >= tloR) { al = denb_step(al, sm[t * 8 + jj], TrB); --t; }
            if (lane < 8) {
                AST(&DR[16 + j], al);
                if (j == 0) AST(&DR[24], __int_as_float(sc));
            }
        }
    } else if (role == 3) {
        // =================== DEN MATRIX FWD: t = tq+1..tm ===================
        // wave wv scans 4 basis columns c = 4*wv + (lane>>4); each 16-lane
        // row holds one column duplicated twice (j = lane&7).
        float* MF = ws + MATF + (size_t)b * 128;
        const int j  = lane & 7;
        const int jj = ((j & 3) << 1) + (j >> 2);
        const int cc = (wv << 2) + (lane >> 4);
        float Tr[8];
#pragma unroll
        for (int r = 0; r < 8; ++r)
            Tr[r] = fexp2(trans[((j - r) & 7) * S + j] * LOG2E);
        float al = (j == cc) ? 1.0f : 0.0f;
        int sc = 0;
        int t = tq + 1;
        if (t + 3 <= tm) {
            float c0 = sm[t * 8 + jj];
            float c1 = sm[(t + 1) * 8 + jj];
            float c2 = sm[(t + 2) * 8 + jj];
            float c3 = sm[(t + 3) * 8 + jj];
            pin();
            while (t + 7 <= tm) {
                float d0 = sm[(t + 4) * 8 + jj];
                float d1 = sm[(t + 5) * 8 + jj];
                float d2 = sm[(t + 6) * 8 + jj];
                float d3 = sm[(t + 7) * 8 + jj];
                pin();
                al = denf_step(al, c0, Tr);
                al = denf_step(al, c1, Tr);
                al = denf_step(al, c2, Tr);
                al = denf_step(al, c3, Tr);
                sc += den_renorm(al);
                c0 = d0; c1 = d1; c2 = d2; c3 = d3;
                t += 4;
            }
            al = denf_step(al, c0, Tr);
            al = denf_step(al, c1, Tr);
            al = denf_step(al, c2, Tr);
            al = denf_step(al, c3, Tr);
            sc += den_renorm(al);
            t += 4;
        }
        while (t <= tm) { al = denf_step(al, sm[t * 8 + jj], Tr); ++t; }
        if ((lane & 15) < 8) {
            AST(&MF[cc * 8 + j], al);
            if (j == 0) AST(&MF[64 + cc], __int_as_float(sc));
        }
    } else {
        // =================== DEN MATRIX BWD: t = tq2..dlo ===================
        float* MB = ws + MATB + (size_t)b * 128;
        const int j  = lane & 7;
        const int jj = ((j & 3) << 1) + (j >> 2);
        const int cc = (wv << 2) + (lane >> 4);
        float TrB[8];
#pragma unroll
        for (int r = 0; r < 8; ++r)
            TrB[r] = fexp2(trans[j * S + ((j + r) & 7)] * LOG2E);
        float al = (j == cc) ? 1.0f : 0.0f;
        int sc = 0;
        int t = tq2;
        if (t - 3 >= dlo) {
            float c0 = sm[t * 8 + jj];
            float c1 = sm[(t - 1) * 8 + jj];
            float c2 = sm[(t - 2) * 8 + jj];
            float c3 = sm[(t - 3) * 8 + jj];
            pin();
            while (t - 7 >= dlo) {
                float d0 = sm[(t - 4) * 8 + jj];
                float d1 = sm[(t - 5) * 8 + jj];
                float d2 = sm[(t - 6) * 8 + jj];
                float d3 = sm[(t - 7) * 8 + jj];
                pin();
                al = denb_step(al, c0, TrB);
                al = denb_step(al, c1, TrB);
                al = denb_step(al, c2, TrB);
                al = denb_step(al, c3, TrB);
                sc += den_renorm(al);
                c0 = d0; c1 = d1; c2 = d2; c3 = d3;
                t -= 4;
            }
            al = denb_step(al, c0, TrB);
            al = denb_step(al, c1, TrB);
            al = denb_step(al, c2, TrB);
            al = denb_step(al, c3, TrB);
            sc += den_renorm(al);
            t -= 4;
        }
        while (t >= dlo) { al = denb_step(al, sm[t * 8 + jj], TrB); --t; }
        if ((lane & 15) < 8) {
            AST(&MB[cc * 8 + j], al);
            if (j == 0) AST(&MB[64 + cc], __int_as_float(sc));
        }
    }

    // ---------------- ticket + winner combine ----------------
    __syncthreads();
    int* wflag = (int*)sm;
    if (tid == 0) {
        __threadfence();
        const int tk = atomicAdd(ticket, 1);
        wflag[0] = (tk == 5 * B - 1) ? 1 : 0;
    }
    __syncthreads();
    if (wflag[0] && tid < 64) {
        __threadfence();
        float acc = 0.0f;
        const int c8 = lane >> 3, j8 = lane & 7;
        for (int bb2 = 0; bb2 < B; ++bb2) {
            // ---- numerator (R15) ----
            const float* nf = ws + 16 + (size_t)bb2 * 640;
            const float* nb = ws + 16 + (size_t)B * 640 + (size_t)bb2 * 640;
            float va = 0.0f, vb = 0.0f;
#pragma unroll
            for (int k = 0; k < 4; ++k)
                va = fmaf(ALD(&nf[lane * 4 + k]), ALD(&nb[lane * 4 + k]), va);
#pragma unroll
            for (int k = 0; k < 4; ++k)
                vb = fmaf(ALD(&nf[256 + lane * 4 + k]),
                          ALD(&nb[256 + lane * 4 + k]), vb);
            const int sa = __float_as_int(ALD(&nf[512 + lane]))
                         + __float_as_int(ALD(&nb[512 + lane]));
            const int sb = __float_as_int(ALD(&nf[576 + lane]))
                         + __float_as_int(ALD(&nb[576 + lane]));
            float pa = (va > 0.0f) ? (flog2(va) + (float)sa) : -3.0e38f;
            float pb = (vb > 0.0f) ? (flog2(vb) + (float)sb) : -3.0e38f;
            float part = lse2(pa, pb);
#pragma unroll
            for (int o = 1; o < 64; o <<= 1)
                part = lse2(part, __shfl_xor(part, o, 64));

            // ---- denominator: (alpha*M_F) . (M_B*beta), exact p2 scales ----
            const float* dr = ws + DENR + (size_t)bb2 * 32;
            const float* mf = ws + MATF + (size_t)bb2 * 128;
            const float* mb = ws + MATB + (size_t)bb2 * 128;
            int s1 = __float_as_int(ALD(&mf[64 + c8]));
            int m1 = s1;
#pragma unroll
            for (int o = 8; o < 64; o <<= 1) {
                int oth = __shfl_xor(m1, o, 64);
                m1 = (oth > m1) ? oth : m1;
            }
            int s2 = __float_as_int(ALD(&mb[64 + c8]));
            int m2 = s2;
#pragma unroll
            for (int o = 8; o < 64; o <<= 1) {
                int oth = __shfl_xor(m2, o, 64);
                m2 = (oth > m2) ? oth : m2;
            }
            float t1 = ALD(&dr[c8]) * ALD(&mf[c8 * 8 + j8])
                     * ldexpf(1.0f, s1 - m1);
#pragma unroll
            for (int o = 8; o < 64; o <<= 1) t1 += __shfl_xor(t1, o, 64);
            float t2 = ALD(&dr[16 + c8]) * ALD(&mb[c8 * 8 + j8])
                     * ldexpf(1.0f, s2 - m2);
#pragma unroll
            for (int o = 8; o < 64; o <<= 1) t2 += __shfl_xor(t2, o, 64);
            float pd = t1 * t2;
#pragma unroll
            for (int o = 1; o < 8; o <<= 1) pd += __shfl_xor(pd, o, 64);
            const int scF = __float_as_int(ALD(&dr[8]));
            const int scB = __float_as_int(ALD(&dr[24]));
            float logden = flog2(fmaxf(pd, 1e-37f))
                         + (float)(scF + scB + m1 + m2);
            if (lane == 0) acc += logden - part;
        }
        if (lane == 0) out[0] = acc * (LN2 / (float)B);
    }
}

extern "C" void kernel_launch(void* const* d_in, const int* in_sizes, int n_in,
                              void* d_out, int out_size, void* d_ws, size_t ws_size,
                              hipStream_t stream)
{
    const float* em      = (const float*)d_in[0];
    const float* trans   = (const float*)d_in[1];
    const float* bos     = (const float*)d_in[2];
    const float* eos     = (const float*)d_in[3];
    const int*   lengths = (const int*)d_in[4];
    const int*   targets = (const int*)d_in[5];
    const int*   tlens   = (const int*)d_in[6];
    float* out = (float*)d_out;
    float* ws  = (float*)d_ws;

    const int B  = in_sizes[4];              // 16
    const int SS = in_sizes[1];              // 64
    int S = 1; while (S * S < SS) ++S;       // 8
    const int T = in_sizes[0] / (B * S);     // 2048
    const int L = in_sizes[5] / B;           // 256

    // num blocks: streams 8*(T+2) + ring (4352 floats EX + 256 ints)
    // den blocks: T*8 + small. Request the max.
    const size_t shmem = (size_t)(8 * (T + 2) + 4352 + 256) * sizeof(float);

    static bool attr_done = false;
    if (!attr_done) {
        (void)hipFuncSetAttribute((const void*)crf_fused,
                                  hipFuncAttributeMaxDynamicSharedMemorySize,
                                  (int)(96 * 1024));
        attr_done = true;
    }

    (void)hipMemsetAsync(ws, 0, 64, stream); // ticket
    hipLaunchKernelGGL(crf_fused, dim3(5 * B), dim3(128), shmem, stream,
                       em, trans, bos, eos, lengths, targets, tlens,
                       ws, out, B, T, S, L);
}